// Round 5
// baseline (121.959 us; speedup 1.0000x reference)
//
#include <hip/hip_runtime.h>
#include <math.h>

// N_PTS=1e6, K_DIM=3, N_BINS=21; wv row = 43 floats (v_tilde[22] | w_tilde[21])
#define NROWS        3000000
#define NPTS         1000000
#define NTHREADS     64                   // 1 wave per block -> NO barriers
#define ROWS_PER_BLK 192                  // 3 rows (= 1 point) per thread
#define NBINS        21
#define NV           22
#define DROW         43
#define F_PER_BLK    (ROWS_PER_BLK * DROW)   // 8256 floats = 33024 B
#define F4_PER_BLK   (F_PER_BLK / 4)         // 2064 = 32*64 + 16
#define NBLOCKS      (NROWS / ROWS_PER_BLK)  // 15625 exact

#define AS1 __attribute__((address_space(1)))
#define AS3 __attribute__((address_space(3)))

__device__ __forceinline__ void gload16(const void* g, void* l) {
    __builtin_amdgcn_global_load_lds((const AS1 void*)g, (AS3 void*)l, 16, 0, 0);
}

__global__ __launch_bounds__(NTHREADS) void pwquad_kernel(
    const float* __restrict__ y,
    const float* __restrict__ wv,
    float* __restrict__ out)
{
    __shared__ float buf[F_PER_BLK];     // 33024 B
    __shared__ float yb[ROWS_PER_BLK];   // 768 B

    const int tid = threadIdx.x;
    const int b   = blockIdx.x;
    const float EPSF = 1.1920929e-07f;   // np.finfo(float32).eps

    // ---- DMA-stage the block's 192 rows + y. LDS dst strictly linear
    // (wave-uniform base + lane*16, m104 constraint). Zero staging VGPRs.
    {
        const float4* s = reinterpret_cast<const float4*>(wv) + (size_t)b * F4_PER_BLK;
        float4* d = reinterpret_cast<float4*>(buf);
#pragma unroll
        for (int it = 0; it < 32; ++it)                 // 32*64 = 2048
            gload16(s + it * NTHREADS + tid, d + it * NTHREADS + tid);
        if (tid < 16)                                    // 16 tail
            gload16(s + 32 * NTHREADS + tid, d + 32 * NTHREADS + tid);
        if (tid < 48)                                    // y: 48 float4 = 192 floats
            gload16(reinterpret_cast<const float4*>(y) + (size_t)b * 48 + tid,
                    reinterpret_cast<float4*>(yb) + tid);
    }
    // Single wave: vmcnt(0) is all the sync we need. Issued before any store,
    // so this never waits on store traffic.
    asm volatile("s_waitcnt vmcnt(0)" ::: "memory");

    // ---- Compute: this thread owns point p = b*64 + tid (rows 3*tid..3*tid+2)
    float logj = 0.f;

    for (int r = 0; r < 3; ++r) {
        const int rrow = 3 * tid + r;
        const float* myrow = &buf[rrow * DROW];   // stride 129 == 1 mod 32 -> conflict-free
        const float yv = yb[rrow];

        // w = exp(w_tilde); normalize
        float w[NBINS];
        float wnorm = 0.f;
#pragma unroll
        for (int j = 0; j < NBINS; ++j) { w[j] = __expf(myrow[NV + j]); wnorm += w[j]; }
        const float invw = 1.0f / wnorm;
#pragma unroll
        for (int j = 0; j < NBINS; ++j) w[j] *= invw;

        // ve = exp(v_tilde); trapezoid normalization
        float v[NV];
#pragma unroll
        for (int i = 0; i < NV; ++i) v[i] = __expf(myrow[i]);
        float T = 0.f;
#pragma unroll
        for (int j = 0; j < NBINS; ++j) T += (v[j] + v[j + 1]) * 0.5f * w[j];
        const float invT = 1.0f / T;
#pragma unroll
        for (int i = 0; i < NV; ++i) v[i] = fmaxf(v[i] * invT, 1e-6f);

        // Edge search: latch last k with vw_k <= y (vw non-decreasing)
        float vw = 0.f, wsum = 0.f;
        float vwe = 0.f, wse = 0.f;
        float v0 = v[0], v1 = v[1], we = w[0];
#pragma unroll
        for (int j = 0; j < 20; ++j) {
            const float inc = (v[j] + v[j + 1]) * 0.5f * w[j];
            vw += inc;
            wsum += w[j];
            const bool q = (vw <= yv);
            vwe = q ? vw       : vwe;
            wse = q ? wsum     : wse;
            v0  = q ? v[j + 1] : v0;
            v1  = q ? v[j + 2] : v1;
            we  = q ? w[j + 1] : we;
        }

        // Quadratic solve
        float a = (v1 - v0) * we;
        const float bq = v0 * we;
        const float cc = vwe - yv;
        a = (fabsf(a) < EPSF) ? EPSF : a;
        const float dd = fmaxf(bq * bq - 2.0f * a * cc, 0.f);
        const float sq = sqrtf(dd);
        const float sol1 = (-bq - sq) / a;
        const float sol2 = (-bq + sq) / a;
        float sol = (sol1 >= 0.f && sol1 < 1.f) ? sol1 : sol2;
        sol = fminf(fmaxf(sol, EPSF), 1.f - EPSF);
        float x = we * sol + wse;
        x = fminf(fmaxf(x, EPSF), 1.f - EPSF);

        out[(size_t)b * ROWS_PER_BLK + rrow] = x;
        logj += __logf(v0 + (v1 - v0) * sol);
    }

    // logj output: one per point, fully coalesced 256 B per block
    out[NROWS + (size_t)b * NTHREADS + tid] = -logj;
}

extern "C" void kernel_launch(void* const* d_in, const int* in_sizes, int n_in,
                              void* d_out, int out_size, void* d_ws, size_t ws_size,
                              hipStream_t stream) {
    const float* y  = (const float*)d_in[0];
    const float* wv = (const float*)d_in[1];
    float* out = (float*)d_out;

    pwquad_kernel<<<NBLOCKS, NTHREADS, 0, stream>>>(y, wv, out);
}

// Round 6
// 105.052 us; speedup vs baseline: 1.1609x; 1.1609x over previous
//
#include <hip/hip_runtime.h>
#include <math.h>

// N_PTS=1e6, K_DIM=3, N_BINS=21; wv row = 43 floats (v_tilde[22] | w_tilde[21])
#define NROWS        3000000
#define NTHREADS     64                   // single wave -> no barriers at all
#define ROWS_PER_BLK 60                   // 20 points; 60*43*4 = 10320 B (16B-aligned/blk)
#define NBINS        21
#define NV           22
#define DROW         43
#define F_PER_BLK    (ROWS_PER_BLK * DROW)   // 2580 floats
#define F4_PER_BLK   (F_PER_BLK / 4)         // 645 = 10*64 + 5
#define NBLOCKS      (NROWS / ROWS_PER_BLK)  // 50000 exact

#define AS1 __attribute__((address_space(1)))
#define AS3 __attribute__((address_space(3)))

__device__ __forceinline__ void gload16(const void* g, void* l) {
    __builtin_amdgcn_global_load_lds((const AS1 void*)g, (AS3 void*)l, 16, 0, 0);
}

__global__ __launch_bounds__(NTHREADS, 4) void pwquad_kernel(
    const float* __restrict__ y,
    const float* __restrict__ wv,
    float* __restrict__ out)
{
    __shared__ float buf[F_PER_BLK];      // 10320 B
    __shared__ float yb[ROWS_PER_BLK];    // 240 B

    const int tid = threadIdx.x;
    const int b   = blockIdx.x;
    const float EPSF = 1.1920929e-07f;    // np.finfo(float32).eps

    // ---- DMA-stage 60 rows + y (no staging VGPRs; LDS dst linear = base+lane*16)
    {
        const float4* s = reinterpret_cast<const float4*>(wv + (size_t)b * F_PER_BLK);
        float4* d = reinterpret_cast<float4*>(buf);
#pragma unroll
        for (int it = 0; it < 10; ++it)                  // 640
            gload16(s + it * NTHREADS + tid, d + it * NTHREADS + tid);
        if (tid < (F4_PER_BLK - 10 * NTHREADS))          // 5 tail
            gload16(s + 10 * NTHREADS + tid, d + 10 * NTHREADS + tid);
        if (tid < (ROWS_PER_BLK / 4))                    // y: 15 float4
            gload16(reinterpret_cast<const float4*>(y + (size_t)b * ROWS_PER_BLK) + tid,
                    reinterpret_cast<float4*>(yb) + tid);
    }
    // Single wave: this is ALL the sync we need, and no stores precede it.
    asm volatile("s_waitcnt vmcnt(0)" ::: "memory");

    float ltv = 0.f;   // this row's log term
    if (tid < ROWS_PER_BLK) {
        const float yv = yb[tid];
        const float* myrow = &buf[tid * DROW];   // banks: 11*r+j mod 32 -> 2-way (free)

        // w = exp(w_tilde); normalize
        float w[NBINS];
        float wnorm = 0.f;
#pragma unroll
        for (int j = 0; j < NBINS; ++j) { w[j] = __expf(myrow[NV + j]); wnorm += w[j]; }
        const float invw = 1.0f / wnorm;
#pragma unroll
        for (int j = 0; j < NBINS; ++j) w[j] *= invw;

        // ve = exp(v_tilde); trapezoid normalization
        float v[NV];
#pragma unroll
        for (int i = 0; i < NV; ++i) v[i] = __expf(myrow[i]);
        float T = 0.f;
#pragma unroll
        for (int j = 0; j < NBINS; ++j) T += (v[j] + v[j + 1]) * 0.5f * w[j];
        const float invT = 1.0f / T;
#pragma unroll
        for (int i = 0; i < NV; ++i) v[i] = fmaxf(v[i] * invT, 1e-6f);

        // Edge search: latch last k with vw_k <= y (vw non-decreasing)
        float vw = 0.f, wsum = 0.f;
        float vwe = 0.f, wse = 0.f;
        float v0 = v[0], v1 = v[1], we = w[0];
#pragma unroll
        for (int j = 0; j < 20; ++j) {
            const float inc = (v[j] + v[j + 1]) * 0.5f * w[j];
            vw += inc;
            wsum += w[j];
            const bool q = (vw <= yv);
            vwe = q ? vw       : vwe;
            wse = q ? wsum     : wse;
            v0  = q ? v[j + 1] : v0;
            v1  = q ? v[j + 2] : v1;
            we  = q ? w[j + 1] : we;
        }

        // Quadratic solve
        float a = (v1 - v0) * we;
        const float bq = v0 * we;
        const float cc = vwe - yv;
        a = (fabsf(a) < EPSF) ? EPSF : a;
        const float dd = fmaxf(bq * bq - 2.0f * a * cc, 0.f);
        const float sq = sqrtf(dd);
        const float sol1 = (-bq - sq) / a;
        const float sol2 = (-bq + sq) / a;
        float sol = (sol1 >= 0.f && sol1 < 1.f) ? sol1 : sol2;
        sol = fminf(fmaxf(sol, EPSF), 1.f - EPSF);
        float x = we * sol + wse;
        x = fminf(fmaxf(x, EPSF), 1.f - EPSF);

        out[(size_t)b * ROWS_PER_BLK + tid] = x;
        ltv = __logf(v0 + (v1 - v0) * sol);
    }

    // logj: intra-wave shuffle sum of 3 consecutive lanes (no LDS, no barrier)
    const float t1 = __shfl(ltv, (tid + 1) & 63);
    const float t2 = __shfl(ltv, (tid + 2) & 63);
    if (tid < ROWS_PER_BLK && (tid % 3) == 0) {
        out[NROWS + (size_t)b * (ROWS_PER_BLK / 3) + tid / 3] = -(ltv + t1 + t2);
    }
}

extern "C" void kernel_launch(void* const* d_in, const int* in_sizes, int n_in,
                              void* d_out, int out_size, void* d_ws, size_t ws_size,
                              hipStream_t stream) {
    const float* y  = (const float*)d_in[0];
    const float* wv = (const float*)d_in[1];
    float* out = (float*)d_out;

    pwquad_kernel<<<NBLOCKS, NTHREADS, 0, stream>>>(y, wv, out);
}